// Round 1
// baseline (222.379 us; speedup 1.0000x reference)
//
#include <hip/hip_runtime.h>

constexpr int       C    = 19;
constexpr long long HW   = 512LL * 1024LL;   // 524288 = 2^19
constexpr long long NPIX = 16LL * HW;        // 8388608
constexpr float     THRESH_F = 0.35667494393873245f;  // -log(0.7) rounded to fp32
constexpr double    FXSCALE  = 4294967296.0;          // 2^32 fixed-point scale

struct Meta {
  unsigned long long sum_above;  // fixed-point sum of losses > THRESH
  unsigned long long gt_sum;     // fixed-point sum of elements strictly above threshold-so-far
  unsigned n_valid;
  unsigned n_above;
  unsigned k;      // running rank within selected bin
  unsigned d0;     // selected top-11-bit digit
  unsigned d01;    // selected top-22-bit prefix
  unsigned n_min;
};

__device__ inline unsigned long long fxq(float v) {
  // exact: v*2^32 is an exact float op (power-of-2 scale), llrintf deterministic
  return (unsigned long long)llrintf(v * 4294967296.0f);
}

__device__ inline void block_acc(unsigned lv, unsigned la, unsigned long long sfx,
                                 unsigned* d_lv, unsigned* d_la, unsigned long long* d_s) {
  for (int o = 32; o > 0; o >>= 1) {
    lv  += __shfl_down(lv, o);
    la  += __shfl_down(la, o);
    sfx += __shfl_down(sfx, o);
  }
  __shared__ unsigned s_lv[4], s_la[4];
  __shared__ unsigned long long s_s[4];
  const int lane = threadIdx.x & 63, wid = threadIdx.x >> 6;
  if (lane == 0) { s_lv[wid] = lv; s_la[wid] = la; s_s[wid] = sfx; }
  __syncthreads();
  if (threadIdx.x == 0) {
    unsigned a = 0, b = 0; unsigned long long s = 0;
    for (int i = 0; i < 4; ++i) { a += s_lv[i]; b += s_la[i]; s += s_s[i]; }
    if (d_lv) atomicAdd(d_lv, a);
    if (d_la) atomicAdd(d_la, b);
    atomicAdd(d_s, s);
  }
}

// Pass 1: fused log-softmax CE. float4 over pixels; 19 coalesced 16B loads per quad.
__global__ __launch_bounds__(256) void ce_kernel(
    const float* __restrict__ logits, const int* __restrict__ labels,
    float* __restrict__ ce, Meta* __restrict__ meta) {
  const long long nq = NPIX >> 2;
  const long long stride = (long long)gridDim.x * blockDim.x;
  unsigned lv = 0, la = 0;
  float sa = 0.f;
  for (long long q = blockIdx.x * (long long)blockDim.x + threadIdx.x; q < nq; q += stride) {
    const long long p = q << 2;
    const long long b = p >> 19;           // HW = 2^19
    const long long r = p & (HW - 1);
    const float* base = logits + b * (C * HW) + r;
    const int4 lb4 = *reinterpret_cast<const int4*>(labels + p);
    const int lb[4] = {lb4.x, lb4.y, lb4.z, lb4.w};
    float v[C][4];
#pragma unroll
    for (int c = 0; c < C; ++c) {
      const float4 t = *reinterpret_cast<const float4*>(base + (long long)c * HW);
      v[c][0] = t.x; v[c][1] = t.y; v[c][2] = t.z; v[c][3] = t.w;
    }
    float m[4], s[4], xl[4], o[4];
#pragma unroll
    for (int j = 0; j < 4; ++j) m[j] = v[0][j];
#pragma unroll
    for (int c = 1; c < C; ++c)
#pragma unroll
      for (int j = 0; j < 4; ++j) m[j] = fmaxf(m[j], v[c][j]);
#pragma unroll
    for (int j = 0; j < 4; ++j) { s[j] = 0.f; xl[j] = 0.f; }
#pragma unroll
    for (int c = 0; c < C; ++c)
#pragma unroll
      for (int j = 0; j < 4; ++j) {
        s[j] += __expf(v[c][j] - m[j]);
        if (lb[j] == c) xl[j] = v[c][j];   // static indexing, no scratch
      }
#pragma unroll
    for (int j = 0; j < 4; ++j) {
      const bool val = (lb[j] != 255);
      const float cj = val ? fmaxf(m[j] + __logf(s[j]) - xl[j], 0.f) : 0.f;
      o[j] = cj;
      lv += val ? 1u : 0u;
      la += (cj > THRESH_F) ? 1u : 0u;
      sa += (cj > THRESH_F) ? cj : 0.f;
    }
    *reinterpret_cast<float4*>(ce + p) = make_float4(o[0], o[1], o[2], o[3]);
  }
  block_acc(lv, la, fxq(sa), &meta->n_valid, &meta->n_above, &meta->sum_above);
}

// Histogram of top-11 bits (all elements).
__global__ __launch_bounds__(256) void hist1_kernel(
    const float4* __restrict__ ce4, unsigned* __restrict__ g_cnt) {
  __shared__ unsigned l_cnt[2048];
  for (int i = threadIdx.x; i < 2048; i += 256) l_cnt[i] = 0;
  __syncthreads();
  const long long nq = NPIX >> 2;
  const long long stride = (long long)gridDim.x * blockDim.x;
  for (long long q = blockIdx.x * (long long)blockDim.x + threadIdx.x; q < nq; q += stride) {
    const float4 vv = ce4[q];
    atomicAdd(&l_cnt[__float_as_uint(vv.x) >> 21], 1u);
    atomicAdd(&l_cnt[__float_as_uint(vv.y) >> 21], 1u);
    atomicAdd(&l_cnt[__float_as_uint(vv.z) >> 21], 1u);
    atomicAdd(&l_cnt[__float_as_uint(vv.w) >> 21], 1u);
  }
  __syncthreads();
  for (int i = threadIdx.x; i < 2048; i += 256)
    if (l_cnt[i]) atomicAdd(&g_cnt[i], l_cnt[i]);
}

// Sum of elements strictly above bin d0 + histogram of middle 11 bits within d0.
__global__ __launch_bounds__(256) void hist2_kernel(
    const float4* __restrict__ ce4, Meta* __restrict__ meta,
    unsigned* __restrict__ g_cnt) {
  __shared__ unsigned l_cnt[2048];
  for (int i = threadIdx.x; i < 2048; i += 256) l_cnt[i] = 0;
  const unsigned d0 = meta->d0;   // written by previous dispatch
  __syncthreads();
  const long long nq = NPIX >> 2;
  const long long stride = (long long)gridDim.x * blockDim.x;
  unsigned long long gs = 0;
  for (long long q = blockIdx.x * (long long)blockDim.x + threadIdx.x; q < nq; q += stride) {
    const float4 vv = ce4[q];
    const float va[4] = {vv.x, vv.y, vv.z, vv.w};
#pragma unroll
    for (int j = 0; j < 4; ++j) {
      const unsigned bits = __float_as_uint(va[j]);
      const unsigned hb = bits >> 21;
      if (hb > d0) gs += fxq(va[j]);
      else if (hb == d0) atomicAdd(&l_cnt[(bits >> 10) & 2047u], 1u);
    }
  }
  __syncthreads();
  for (int i = threadIdx.x; i < 2048; i += 256)
    if (l_cnt[i]) atomicAdd(&g_cnt[i], l_cnt[i]);
  block_acc(0u, 0u, gs, nullptr, nullptr, &meta->gt_sum);
}

// Sum of elements in d0 with mid-digit > d1 + cnt/sum histogram of low 10 bits within (d0,d1).
__global__ __launch_bounds__(256) void hist3_kernel(
    const float4* __restrict__ ce4, Meta* __restrict__ meta,
    unsigned* __restrict__ g_cnt, unsigned long long* __restrict__ g_sum) {
  __shared__ unsigned l_cnt[1024];
  __shared__ unsigned long long l_sum[1024];
  for (int i = threadIdx.x; i < 1024; i += 256) { l_cnt[i] = 0; l_sum[i] = 0; }
  const unsigned d01 = meta->d01;
  const unsigned d0 = d01 >> 11;
  __syncthreads();
  const long long nq = NPIX >> 2;
  const long long stride = (long long)gridDim.x * blockDim.x;
  unsigned long long gs = 0;
  for (long long q = blockIdx.x * (long long)blockDim.x + threadIdx.x; q < nq; q += stride) {
    const float4 vv = ce4[q];
    const float va[4] = {vv.x, vv.y, vv.z, vv.w};
#pragma unroll
    for (int j = 0; j < 4; ++j) {
      const unsigned bits = __float_as_uint(va[j]);
      if ((bits >> 21) == d0) {
        const unsigned hl = bits >> 10;
        if (hl > d01) gs += fxq(va[j]);
        else if (hl == d01) {
          atomicAdd(&l_cnt[bits & 1023u], 1u);
          atomicAdd(&l_sum[bits & 1023u], fxq(va[j]));
        }
      }
    }
  }
  __syncthreads();
  for (int i = threadIdx.x; i < 1024; i += 256)
    if (l_cnt[i]) { atomicAdd(&g_cnt[i], l_cnt[i]); atomicAdd(&g_sum[i], l_sum[i]); }
  block_acc(0u, 0u, gs, nullptr, nullptr, &meta->gt_sum);
}

// Descending-order selection scan over a histogram. Single block of 256 threads.
template<int NBINS, int PASS>
__global__ __launch_bounds__(256) void scan_kernel(
    Meta* __restrict__ meta, const unsigned* __restrict__ cnt,
    const unsigned long long* __restrict__ sums, float* __restrict__ out) {
  constexpr int CHUNK = NBINS / 256;
  const int t = threadIdx.x;
  const unsigned nv = meta->n_valid;
  unsigned k;
  if (PASS == 1) { const unsigned nm = nv >> 4; k = nm ? nm : 1u; }
  else k = meta->k;

  unsigned c[CHUNK];
  unsigned long long s[CHUNK];
  unsigned tc = 0; unsigned long long ts = 0;
#pragma unroll
  for (int i = 0; i < CHUNK; ++i) {
    c[i] = cnt[t * CHUNK + i];
    s[i] = 0ull;
    if (PASS == 3) s[i] = sums[t * CHUNK + i];
    tc += c[i]; ts += s[i];
  }
  __shared__ unsigned sc[256];
  __shared__ unsigned long long ssm[256];
  sc[t] = tc; ssm[t] = ts;
  __syncthreads();             // also orders the meta->k read above vs. the write below
  unsigned ac = 0; unsigned long long as = 0;
  for (int j = t + 1; j < 256; ++j) { ac += sc[j]; if (PASS == 3) as += ssm[j]; }
#pragma unroll
  for (int i = CHUNK - 1; i >= 0; --i) {
    if (ac < k && ac + c[i] >= k) {     // unique (thread,bin): crossing point
      const unsigned D = (unsigned)(t * CHUNK + i);
      if (PASS == 1)      { meta->n_min = nv >> 4; meta->d0 = D; meta->k = k - ac; }
      else if (PASS == 2) { meta->d01 = (meta->d0 << 11) | D; meta->k = k - ac; }
      else {
        const unsigned T = (meta->d01 << 10) | D;
        const float tv = __uint_as_float(T);
        const unsigned long long gt_s = meta->gt_sum + as;   // sum of all elements > T
        const unsigned ties = k - ac;                        // # elements == T included
        const double topk = ((double)gt_s + (double)ties * (double)fxq(tv)) / FXSCALE;
        const unsigned n_min = meta->n_min;
        const unsigned n_ab  = meta->n_above;
        const double mean_topk = topk / (double)(n_min ? n_min : 1u);
        const double mean_ab = ((double)meta->sum_above / FXSCALE) / (double)(n_ab ? n_ab : 1u);
        // cond: loss[n_min] > THRESH  <=>  n_above > n_min (strict order, exact w/ ties)
        out[0] = (float)((n_ab > n_min) ? mean_ab : mean_topk);
      }
    }
    ac += c[i];
    if (PASS == 3) as += s[i];
  }
}

extern "C" void kernel_launch(void* const* d_in, const int* in_sizes, int n_in,
                              void* d_out, int out_size, void* d_ws, size_t ws_size,
                              hipStream_t stream) {
  (void)in_sizes; (void)n_in; (void)out_size; (void)ws_size;
  const float* logits = (const float*)d_in[0];
  const int*   labels = (const int*)d_in[1];
  float* out = (float*)d_out;

  char* ws = (char*)d_ws;
  float* ce = (float*)ws;
  size_t off = (size_t)NPIX * 4;
  const size_t meta_base = off;
  Meta* meta = (Meta*)(ws + off);                      off += 64;
  unsigned long long* h2s = (unsigned long long*)(ws + off); off += 1024 * 8;
  unsigned* h0c = (unsigned*)(ws + off);               off += 2048 * 4;
  unsigned* h1c = (unsigned*)(ws + off);               off += 2048 * 4;
  unsigned* h2c = (unsigned*)(ws + off);               off += 1024 * 4;

  hipMemsetAsync(ws + meta_base, 0, off - meta_base, stream);

  ce_kernel<<<2048, 256, 0, stream>>>(logits, labels, ce, meta);
  hist1_kernel<<<512, 256, 0, stream>>>((const float4*)ce, h0c);
  scan_kernel<2048, 1><<<1, 256, 0, stream>>>(meta, h0c, nullptr, out);
  hist2_kernel<<<512, 256, 0, stream>>>((const float4*)ce, meta, h1c);
  scan_kernel<2048, 2><<<1, 256, 0, stream>>>(meta, h1c, nullptr, out);
  hist3_kernel<<<512, 256, 0, stream>>>((const float4*)ce, meta, h2c, h2s);
  scan_kernel<1024, 3><<<1, 256, 0, stream>>>(meta, h2c, h2s, out);
}

// Round 2
// 179.367 us; speedup vs baseline: 1.2398x; 1.2398x over previous
//
#include <hip/hip_runtime.h>

constexpr int       C    = 19;
constexpr long long HW   = 512LL * 1024LL;   // 2^19
constexpr long long NPIX = 16LL * HW;        // 8388608
constexpr float     THRESH_F = 0.35667494393873245f;  // -log(0.7)
constexpr double    FXSCALE  = 4294967296.0;          // 2^32

struct Meta {
  unsigned long long sum_above;  // fixed-point sum of losses > THRESH
  unsigned long long sum_all;    // fixed-point sum of all losses (n_min==0 corner)
  unsigned long long gt_sum;     // fixed-point sum of elements above running threshold
  unsigned n_valid;
  unsigned n_above;
  unsigned done;                 // 1 = answer already written (branch A / corner)
};

__device__ inline unsigned long long fxq(float v) {
  return (unsigned long long)llrintf(v * 4294967296.0f);
}

// ---- block reduction helpers -------------------------------------------------

__device__ inline void block_acc4(unsigned lv, unsigned la,
                                  unsigned long long s1, unsigned long long s2,
                                  Meta* meta) {
  for (int o = 32; o > 0; o >>= 1) {
    lv += __shfl_down(lv, o); la += __shfl_down(la, o);
    s1 += __shfl_down(s1, o); s2 += __shfl_down(s2, o);
  }
  __shared__ unsigned a1[4], a2[4];
  __shared__ unsigned long long b1[4], b2[4];
  const int lane = threadIdx.x & 63, wid = threadIdx.x >> 6;
  if (lane == 0) { a1[wid] = lv; a2[wid] = la; b1[wid] = s1; b2[wid] = s2; }
  __syncthreads();
  if (threadIdx.x == 0) {
    unsigned x = 0, y = 0; unsigned long long u = 0, v = 0;
    for (int i = 0; i < 4; ++i) { x += a1[i]; y += a2[i]; u += b1[i]; v += b2[i]; }
    atomicAdd(&meta->n_valid, x); atomicAdd(&meta->n_above, y);
    atomicAdd(&meta->sum_above, u); atomicAdd(&meta->sum_all, v);
  }
}

__device__ inline void block_acc_u64(unsigned long long s, unsigned long long* dst) {
  for (int o = 32; o > 0; o >>= 1) s += __shfl_down(s, o);
  __shared__ unsigned long long b[4];
  const int lane = threadIdx.x & 63, wid = threadIdx.x >> 6;
  if (lane == 0) b[wid] = s;
  __syncthreads();
  if (threadIdx.x == 0) {
    unsigned long long u = 0;
    for (int i = 0; i < 4; ++i) u += b[i];
    atomicAdd(dst, u);
  }
}

// Descending-order selection over a histogram, run redundantly by one block.
// Returns bin D and rem = k - count(bins > D); broadcast to all threads.
template<int NBINS>
__device__ inline void scan_desc(const unsigned* __restrict__ cnt, unsigned k,
                                 unsigned* outD, unsigned* outRem) {
  constexpr int CHUNK = NBINS / 256;
  const int t = threadIdx.x;
  __shared__ unsigned sc[256];
  __shared__ unsigned sD, sRem;
  __syncthreads();   // protect reuse across consecutive calls
  unsigned c[CHUNK]; unsigned tc = 0;
#pragma unroll
  for (int i = 0; i < CHUNK; ++i) { c[i] = cnt[t * CHUNK + i]; tc += c[i]; }
  sc[t] = tc;
  __syncthreads();
  unsigned ac = 0;
  for (int j = t + 1; j < 256; ++j) ac += sc[j];
#pragma unroll
  for (int i = CHUNK - 1; i >= 0; --i) {
    if (ac < k && ac + c[i] >= k) { sD = (unsigned)(t * CHUNK + i); sRem = k - ac; }
    ac += c[i];
  }
  __syncthreads();
  *outD = sD; *outRem = sRem;
}

// ---- CE computation (identical math to the R1-passing version) ---------------

__device__ inline void compute_ce4(const float* __restrict__ logits,
                                   const int* __restrict__ labels,
                                   long long p, float o[4], int lb[4]) {
  const long long b = p >> 19;
  const long long r = p & (HW - 1);
  const float* base = logits + b * (C * HW) + r;
  const int4 lb4 = *reinterpret_cast<const int4*>(labels + p);
  lb[0] = lb4.x; lb[1] = lb4.y; lb[2] = lb4.z; lb[3] = lb4.w;
  float v[C][4];
#pragma unroll
  for (int c = 0; c < C; ++c) {
    const float4 t = *reinterpret_cast<const float4*>(base + (long long)c * HW);
    v[c][0] = t.x; v[c][1] = t.y; v[c][2] = t.z; v[c][3] = t.w;
  }
  float m[4], s[4], xl[4];
#pragma unroll
  for (int j = 0; j < 4; ++j) m[j] = v[0][j];
#pragma unroll
  for (int c = 1; c < C; ++c)
#pragma unroll
    for (int j = 0; j < 4; ++j) m[j] = fmaxf(m[j], v[c][j]);
#pragma unroll
  for (int j = 0; j < 4; ++j) { s[j] = 0.f; xl[j] = 0.f; }
#pragma unroll
  for (int c = 0; c < C; ++c)
#pragma unroll
    for (int j = 0; j < 4; ++j) {
      s[j] += __expf(v[c][j] - m[j]);
      if (lb[j] == c) xl[j] = v[c][j];
    }
#pragma unroll
  for (int j = 0; j < 4; ++j) {
    const bool val = (lb[j] != 255);
    o[j] = val ? fmaxf(m[j] + __logf(s[j]) - xl[j], 0.f) : 0.f;
  }
}

// Pass 1: streaming reduction only — no ce store.
__global__ __launch_bounds__(256) void ce_reduce_kernel(
    const float* __restrict__ logits, const int* __restrict__ labels,
    Meta* __restrict__ meta) {
  const long long nq = NPIX >> 2;
  const long long stride = (long long)gridDim.x * blockDim.x;
  unsigned lv = 0, la = 0;
  float sa = 0.f, st = 0.f;
  for (long long q = blockIdx.x * (long long)blockDim.x + threadIdx.x; q < nq; q += stride) {
    float o[4]; int lb[4];
    compute_ce4(logits, labels, q << 2, o, lb);
#pragma unroll
    for (int j = 0; j < 4; ++j) {
      const bool val = (lb[j] != 255);
      lv += val ? 1u : 0u;
      la += (o[j] > THRESH_F) ? 1u : 0u;
      sa += (o[j] > THRESH_F) ? o[j] : 0.f;
      st += val ? o[j] : 0.f;
    }
  }
  block_acc4(lv, la, fxq(sa), fxq(st), meta);
}

// Decide branch on-device. Branch A (or n_min==0 corner): write answer, set done.
__global__ void decide_kernel(Meta* __restrict__ meta, float* __restrict__ out) {
  if (threadIdx.x == 0) {
    const unsigned nv = meta->n_valid, na = meta->n_above;
    const unsigned nm = nv >> 4;
    if (na > nm) {            // cond: loss[n_min] > THRESH
      out[0] = (float)(((double)meta->sum_above / FXSCALE) / (double)na);
      meta->done = 1u;
    } else if (nm == 0u) {    // reference: take(csum, -1) / max(n_min,1)
      out[0] = (float)((double)meta->sum_all / FXSCALE);
      meta->done = 1u;
    } else {
      meta->done = 0u;
    }
  }
}

// ---- Branch-B fallback: recompute CE, store, radix-select top-k sum ----------

__global__ __launch_bounds__(256) void ce_write_hist1(
    const float* __restrict__ logits, const int* __restrict__ labels,
    const Meta* __restrict__ meta, float* __restrict__ ce,
    unsigned* __restrict__ g_cnt) {
  if (meta->done) return;
  __shared__ unsigned l_cnt[2048];
  for (int i = threadIdx.x; i < 2048; i += 256) l_cnt[i] = 0;
  __syncthreads();
  const long long nq = NPIX >> 2;
  const long long stride = (long long)gridDim.x * blockDim.x;
  for (long long q = blockIdx.x * (long long)blockDim.x + threadIdx.x; q < nq; q += stride) {
    float o[4]; int lb[4];
    const long long p = q << 2;
    compute_ce4(logits, labels, p, o, lb);
    *reinterpret_cast<float4*>(ce + p) = make_float4(o[0], o[1], o[2], o[3]);
#pragma unroll
    for (int j = 0; j < 4; ++j) atomicAdd(&l_cnt[__float_as_uint(o[j]) >> 21], 1u);
  }
  __syncthreads();
  for (int i = threadIdx.x; i < 2048; i += 256)
    if (l_cnt[i]) atomicAdd(&g_cnt[i], l_cnt[i]);
}

__global__ __launch_bounds__(256) void hist2_kernel(
    const float4* __restrict__ ce4, Meta* __restrict__ meta,
    const unsigned* __restrict__ h0c, unsigned* __restrict__ g_cnt) {
  if (meta->done) return;
  const unsigned nm = meta->n_valid >> 4;
  unsigned d0, k1;
  scan_desc<2048>(h0c, nm, &d0, &k1);
  __shared__ unsigned l_cnt[2048];
  for (int i = threadIdx.x; i < 2048; i += 256) l_cnt[i] = 0;
  __syncthreads();
  const long long nq = NPIX >> 2;
  const long long stride = (long long)gridDim.x * blockDim.x;
  unsigned long long gs = 0;
  for (long long q = blockIdx.x * (long long)blockDim.x + threadIdx.x; q < nq; q += stride) {
    const float4 vv = ce4[q];
    const float va[4] = {vv.x, vv.y, vv.z, vv.w};
#pragma unroll
    for (int j = 0; j < 4; ++j) {
      const unsigned bits = __float_as_uint(va[j]);
      const unsigned hb = bits >> 21;
      if (hb > d0) gs += fxq(va[j]);
      else if (hb == d0) atomicAdd(&l_cnt[(bits >> 10) & 2047u], 1u);
    }
  }
  __syncthreads();
  for (int i = threadIdx.x; i < 2048; i += 256)
    if (l_cnt[i]) atomicAdd(&g_cnt[i], l_cnt[i]);
  block_acc_u64(gs, &meta->gt_sum);
}

__global__ __launch_bounds__(256) void hist3_kernel(
    const float4* __restrict__ ce4, Meta* __restrict__ meta,
    const unsigned* __restrict__ h0c, const unsigned* __restrict__ h1c,
    unsigned* __restrict__ g_cnt, unsigned long long* __restrict__ g_sum) {
  if (meta->done) return;
  const unsigned nm = meta->n_valid >> 4;
  unsigned d0, k1, d1, k2;
  scan_desc<2048>(h0c, nm, &d0, &k1);
  scan_desc<2048>(h1c, k1, &d1, &k2);
  const unsigned d01 = (d0 << 11) | d1;
  __shared__ unsigned l_cnt[1024];
  __shared__ unsigned long long l_sum[1024];
  for (int i = threadIdx.x; i < 1024; i += 256) { l_cnt[i] = 0; l_sum[i] = 0; }
  __syncthreads();
  const long long nq = NPIX >> 2;
  const long long stride = (long long)gridDim.x * blockDim.x;
  unsigned long long gs = 0;
  for (long long q = blockIdx.x * (long long)blockDim.x + threadIdx.x; q < nq; q += stride) {
    const float4 vv = ce4[q];
    const float va[4] = {vv.x, vv.y, vv.z, vv.w};
#pragma unroll
    for (int j = 0; j < 4; ++j) {
      const unsigned bits = __float_as_uint(va[j]);
      if ((bits >> 21) == d0) {
        const unsigned hl = bits >> 10;
        if (hl > d01) gs += fxq(va[j]);
        else if (hl == d01) {
          atomicAdd(&l_cnt[bits & 1023u], 1u);
          atomicAdd(&l_sum[bits & 1023u], fxq(va[j]));
        }
      }
    }
  }
  __syncthreads();
  for (int i = threadIdx.x; i < 1024; i += 256)
    if (l_cnt[i]) { atomicAdd(&g_cnt[i], l_cnt[i]); atomicAdd(&g_sum[i], l_sum[i]); }
  block_acc_u64(gs, &meta->gt_sum);
}

__global__ __launch_bounds__(256) void final_kernel(
    Meta* __restrict__ meta, const unsigned* __restrict__ h0c,
    const unsigned* __restrict__ h1c, const unsigned* __restrict__ h2c,
    const unsigned long long* __restrict__ h2s, float* __restrict__ out) {
  if (meta->done) return;
  const unsigned nm = meta->n_valid >> 4;
  unsigned d0, k1, d1, k2;
  scan_desc<2048>(h0c, nm, &d0, &k1);
  scan_desc<2048>(h1c, k1, &d1, &k2);
  const unsigned d01 = (d0 << 11) | d1;

  const int t = threadIdx.x;
  unsigned c[4]; unsigned long long s[4];
  unsigned tc = 0; unsigned long long ts = 0;
#pragma unroll
  for (int i = 0; i < 4; ++i) {
    c[i] = h2c[t * 4 + i]; s[i] = h2s[t * 4 + i]; tc += c[i]; ts += s[i];
  }
  __shared__ unsigned sc[256];
  __shared__ unsigned long long ssm[256];
  __syncthreads();
  sc[t] = tc; ssm[t] = ts;
  __syncthreads();
  unsigned ac = 0; unsigned long long as = 0;
  for (int j = t + 1; j < 256; ++j) { ac += sc[j]; as += ssm[j]; }
#pragma unroll
  for (int i = 3; i >= 0; --i) {
    if (ac < k2 && ac + c[i] >= k2) {       // unique crossing thread/bin
      const unsigned T = (d01 << 10) | (unsigned)(t * 4 + i);
      const float tv = __uint_as_float(T);
      const unsigned long long gt_s = meta->gt_sum + as;  // sum of elements > T
      const unsigned ties = k2 - ac;                      // # elements == T kept
      const double topk = ((double)gt_s + (double)ties * (double)fxq(tv)) / FXSCALE;
      out[0] = (float)(topk / (double)nm);
    }
    ac += c[i]; as += s[i];
  }
}

extern "C" void kernel_launch(void* const* d_in, const int* in_sizes, int n_in,
                              void* d_out, int out_size, void* d_ws, size_t ws_size,
                              hipStream_t stream) {
  (void)in_sizes; (void)n_in; (void)out_size; (void)ws_size;
  const float* logits = (const float*)d_in[0];
  const int*   labels = (const int*)d_in[1];
  float* out = (float*)d_out;

  char* ws = (char*)d_ws;
  float* ce = (float*)ws;                       // 33.5 MB, used only in branch B
  size_t off = (size_t)NPIX * 4;
  const size_t meta_base = off;
  Meta* meta = (Meta*)(ws + off);                            off += 64;
  unsigned long long* h2s = (unsigned long long*)(ws + off); off += 1024 * 8;
  unsigned* h0c = (unsigned*)(ws + off);                     off += 2048 * 4;
  unsigned* h1c = (unsigned*)(ws + off);                     off += 2048 * 4;
  unsigned* h2c = (unsigned*)(ws + off);                     off += 1024 * 4;

  hipMemsetAsync(ws + meta_base, 0, off - meta_base, stream);

  ce_reduce_kernel<<<2048, 256, 0, stream>>>(logits, labels, meta);
  decide_kernel<<<1, 64, 0, stream>>>(meta, out);
  ce_write_hist1<<<2048, 256, 0, stream>>>(logits, labels, meta, ce, h0c);
  hist2_kernel<<<512, 256, 0, stream>>>((const float4*)ce, meta, h0c, h1c);
  hist3_kernel<<<512, 256, 0, stream>>>((const float4*)ce, meta, h0c, h1c, h2c, h2s);
  final_kernel<<<1, 256, 0, stream>>>(meta, h0c, h1c, h2c, h2s, out);
}